// Round 11
// baseline (293.985 us; speedup 1.0000x reference)
//
#include <hip/hip_runtime.h>
#include <math.h>

#define BLK 256   // prep kernels
#define MBLK 512  // gat_main: 8 waves

constexpr int Bg    = 2048;
constexpr int Fn    = 64;
constexpr int DIN   = 32;
constexpr int Hd    = 128;
constexpr int HEADS = 4;
constexpr int NC    = 16;
constexpr int EPG   = 128;
constexpr int Etot  = Bg * EPG;
constexpr int W1C   = HEADS * Hd;   // 512
constexpr int NSTR  = 68;           // hT row stride (bf16)
constexpr int EROW  = 132;          // eluS row stride
constexpr int PROW  = 68;           // Pbf row stride; row bytes [128,132) hold f32 softmax sum
constexpr int NE    = EPG + Fn;     // 192 edges incl self-loops

typedef __attribute__((ext_vector_type(8))) __bf16 bf16x8;
typedef __attribute__((ext_vector_type(4))) __bf16 bf16x4;
typedef __attribute__((ext_vector_type(4))) float  f32x4;

// ---- precomputed weights ----
__device__ __align__(16) __bf16 g_wcombT[W1C * DIN];
__device__ float g_c1[W1C];
__device__ float g_c1s[16];
__device__ __align__(16) __bf16 g_w1F[HEADS*8*64*8];        // 16384 elems
__device__ __align__(16) __bf16 g_w2F[HEADS*4*8*64*8];      // 65536 elems
__device__ __align__(16) __bf16 g_wscF[HEADS*4*64*8];       // 8192 elems
__device__ __align__(16) __bf16 g_bs1F[64*8];               // 512 elems

// ================= prep1: wcombT + c1 (R6-verified) =================
__global__ __launch_bounds__(BLK) void prep1(
    const float* __restrict__ Wa, const float* __restrict__ ba,
    const float* __restrict__ W1)
{
  __shared__ float WaS[DIN * Hd];                       // Wa transposed [m][k], 16 KB
  const int tid = threadIdx.x;
  for (int i = tid; i < DIN * Hd; i += BLK) {
    int k = i >> 7, m = i & 127;                        // coalesced read of Wa
    WaS[m * DIN + k] = Wa[i];
  }
  __syncthreads();

  int i = blockIdx.x * BLK + tid;
  if (i < DIN * W1C) {                                  // wcombT: i = n*32+k (coalesced write)
    int k = i & 31, n = i >> 5;
    float a0 = 0.f, a1 = 0.f, a2 = 0.f, a3 = 0.f;
    #pragma unroll
    for (int m = 0; m < Hd; m += 4) {
      a0 += WaS[(m  )*DIN + k] * W1[(m  )*W1C + n];
      a1 += WaS[(m+1)*DIN + k] * W1[(m+1)*W1C + n];
      a2 += WaS[(m+2)*DIN + k] * W1[(m+2)*W1C + n];
      a3 += WaS[(m+3)*DIN + k] * W1[(m+3)*W1C + n];
    }
    g_wcombT[i] = (__bf16)(a0 + a1 + a2 + a3);
  } else if (i < DIN*W1C + W1C) {                       // c1
    int n = i - DIN*W1C;
    float a0 = 0.f, a1 = 0.f, a2 = 0.f, a3 = 0.f;
    #pragma unroll
    for (int m = 0; m < Hd; m += 4) {
      a0 += ba[m  ] * W1[(m  )*W1C + n];
      a1 += ba[m+1] * W1[(m+1)*W1C + n];
      a2 += ba[m+2] * W1[(m+2)*W1C + n];
      a3 += ba[m+3] * W1[(m+3)*W1C + n];
    }
    g_c1[n] = a0 + a1 + a2 + a3;
  }
}

// ================= prep2: all fragment-major tables (R6-verified) =================
constexpr int R_W2F  = 65536;
constexpr int R_W1F  = 16384;
constexpr int R_WSCZ = 8192;
constexpr int R_WSCD = 4096;
constexpr int R_BS1Z = 512;
constexpr int R_BS1D = 1024;
constexpr int R_C1S  = 128;
constexpr int B0 = R_W2F;
constexpr int B1 = B0 + R_W1F;
constexpr int B2 = B1 + R_WSCZ;
constexpr int B3 = B2 + R_WSCD;
constexpr int B4 = B3 + R_BS1Z;
constexpr int B5 = B4 + R_BS1D;
constexpr int P2_TOT = B5 + R_C1S;                      // 95872

__global__ __launch_bounds__(BLK) void prep2(
    const float* __restrict__ W2,
    const float* __restrict__ as1, const float* __restrict__ ad1,
    const float* __restrict__ as2, const float* __restrict__ ad2)
{
  int i = blockIdx.x * BLK + threadIdx.x;
  if (i < B0) {                                         // w2F
    int k = i >> 7, n = i & 127;
    int hh = k >> 7, Ks = (k >> 5) & 3, q = (k >> 3) & 3, j = k & 7;
    int Nt = n >> 4, l = n & 15;
    int idx = (((hh*4 + Ks)*8 + Nt)*64 + (q*16 + l))*8 + j;
    g_w2F[idx] = (__bf16)W2[i];
  } else if (i < B1) {                                  // w1F
    int j = i - B0;
    int jj = j & 7, lane = (j >> 3) & 63, T = j >> 9;
    int hh = T >> 3, Nt = T & 7;
    int q = lane >> 4, l = lane & 15;
    g_w1F[j] = g_wcombT[(hh*Hd + Nt*16 + l)*DIN + q*8 + jj];
  } else if (i < B2) {                                  // wscF zero cells
    int j = i - B1;
    int lane = (j >> 3) & 63, c = lane & 15;
    if (c >= 2) g_wscF[j] = (__bf16)0.f;
  } else if (i < B3) {                                  // wscF dots
    int j = i - B2;
    int p = j & 3, c = (j >> 2) & 1, k = j >> 3;
    const float* av = c ? ad2 : as2;
    float a0 = 0.f, a1 = 0.f, a2 = 0.f, a3 = 0.f;
    #pragma unroll
    for (int q = 0; q < 32; q += 4) {
      int f = p*32 + q;
      a0 += W2[(size_t)k*Hd + f    ] * av[f    ];
      a1 += W2[(size_t)k*Hd + f + 1] * av[f + 1];
      a2 += W2[(size_t)k*Hd + f + 2] * av[f + 2];
      a3 += W2[(size_t)k*Hd + f + 3] * av[f + 3];
    }
    float a = a0 + a1 + a2 + a3;
    a += __shfl_xor(a, 1);
    a += __shfl_xor(a, 2);
    if (p == 0) {
      int T = k >> 5, q2 = (k >> 3) & 3, jj = k & 7;
      g_wscF[(T*64 + q2*16 + c)*8 + jj] = (__bf16)a;
    }
  } else if (i < B4) {                                  // bs1F zero cells
    int j = i - B3;
    int lane = j >> 3, c = lane & 15;
    if (c >= 8) g_bs1F[j] = (__bf16)0.f;
  } else if (i < B5) {                                  // bs1F dots
    int j = i - B4;
    int p = j & 3, c = (j >> 2) & 7, kk = j >> 5;
    int h = c >> 1;
    const float* av = (c & 1) ? (ad1 + h*Hd) : (as1 + h*Hd);
    float a0 = 0.f, a1 = 0.f, a2 = 0.f, a3 = 0.f;
    #pragma unroll
    for (int q = 0; q < 32; q += 4) {
      int f = p*32 + q;
      a0 += (float)g_wcombT[(h*Hd + f    )*DIN + kk] * av[f    ];
      a1 += (float)g_wcombT[(h*Hd + f + 1)*DIN + kk] * av[f + 1];
      a2 += (float)g_wcombT[(h*Hd + f + 2)*DIN + kk] * av[f + 2];
      a3 += (float)g_wcombT[(h*Hd + f + 3)*DIN + kk] * av[f + 3];
    }
    float a = a0 + a1 + a2 + a3;
    a += __shfl_xor(a, 1);
    a += __shfl_xor(a, 2);
    if (p == 0) {
      int q2 = kk >> 3, jj = kk & 7;
      g_bs1F[(q2*16 + c)*8 + jj] = (__bf16)a;
    }
  } else if (i < P2_TOT) {                              // c1s
    int j = i - B5;
    int p = j & 7, c = j >> 3;
    float a = 0.f;
    if (c < 8) {
      int h = c >> 1;
      const float* av = (c & 1) ? (ad1 + h*Hd) : (as1 + h*Hd);
      #pragma unroll
      for (int q = 0; q < 16; ++q) {
        int f = p*16 + q;
        a += g_c1[h*Hd + f] * av[f];
      }
    }
    a += __shfl_xor(a, 1);
    a += __shfl_xor(a, 2);
    a += __shfl_xor(a, 4);
    if (p == 0) g_c1s[c] = a;
  }
}

// ================= main fused kernel: 8-WAVE variant =================
// R10 failed from a zeroing bug (Pbf tail 1024..1087 float4 never zeroed ->
// garbage P rows 56-63 in buffer 1, absmax 2.31). Fixed here: 512+512+64.
// Experiment unchanged: 512 threads, 24 waves/CU (6/SIMD), half-length
// per-wave chains, same LDS map (53760B -> 3 blocks/CU).
#define SUMP(buf, t) ((float*)((char*)&Pbf[buf][(t)*PROW] + 128))
#define RCP(x) __builtin_amdgcn_rcpf(x)
__global__ __launch_bounds__(MBLK, 6) void gat_main(
    const float* __restrict__ emb, const int* __restrict__ ei,
    const float* __restrict__ gate_logits,
    const float* __restrict__ b1, const float* __restrict__ b2,
    const float* __restrict__ Wc1, const float* __restrict__ bc1,
    const float* __restrict__ Wc2, const float* __restrict__ bc2,
    float* __restrict__ out)
{
  __shared__ __align__(16) __bf16 hT[Hd * NSTR];      // 17408: h^T [feature][node]
  __shared__ __align__(16) __bf16 eluS[Fn * EROW];    // 16896: elu [node][feat]; cells+gateS alias
  __shared__ __align__(16) __bf16 Pbf[2][Fn * PROW];  // 17408: P dbuf; padding = sums; [1] = tail
  __shared__ float sS1s[HEADS][Fn], sS1d[HEADS][Fn];  // 2048: layer-1 scores

  unsigned* cells = (unsigned*)eluS;                  // bytes [0,16384) of eluS (setup only)
  float*   gateS  = (float*)(eluS + 8192);            // bytes [16384,16640) of eluS
  float*   sSrc   = (float*)&Pbf[1][0];               // tail aliases (Pbf[1] dead after C(3))
  float*   sDst   = sSrc + Fn;
  __bf16*  wS     = (__bf16*)(sDst + Fn);             // byte 512 in Pbf[1]: 16-aligned
  float*   gpool  = (float*)(wS + Fn);
  float*   hcS    = gpool + Hd;

  const int b    = blockIdx.x;
  const int tid  = threadIdx.x;
  const int lane = tid & 63;
  const int wv   = tid >> 6;          // 0..7
  const int ng   = wv & 3;            // node group (16 nodes)
  const int nh   = wv >> 2;           // N-half (0/1)
  const int quad = lane >> 4;
  const int l15  = lane & 15;
  const int nodeBase = ng * 16;
  const int m0   = wv * 16;           // 16-feature band for C/G
  const int base = b * Fn;

  const f32x4 zero4 = {0.f, 0.f, 0.f, 0.f};

  // ---- S1a: zero cells + both Pbf buffers (incl padded sums), gate, edges, emb ----
  int es = 0, et = 0, ecell = 0;
  if (tid < NE) {
    if (tid < EPG) {
      es = ei[(size_t)b*EPG + tid] - base;
      et = ei[(size_t)Etot + (size_t)b*EPG + tid] - base;
    } else {
      es = et = tid - EPG;
    }
    ecell = et * Fn + es;
  }
  {
    float4* c4 = (float4*)cells;                      // 16384B = 1024 float4
    const float4 z4 = {0.f,0.f,0.f,0.f};
    c4[tid] = z4; c4[tid + 512] = z4;
  }
  {
    float4* p4 = (float4*)&Pbf[0][0];                 // 2*8704B = 1088 float4
    const float4 z4 = {0.f,0.f,0.f,0.f};
    p4[tid] = z4; p4[tid + 512] = z4;                 // 0..1023
    if (tid < 64) p4[1024 + tid] = z4;                // 1024..1087 (R10 bug: was missing)
  }
  if (tid < Fn) {
    float g = 1.f / (1.f + expf(-gate_logits[tid]));
    gateS[tid] = g;
    if (b == 0) out[Bg*NC + tid] = g;                 // second tuple output (gate)
  }
  float4 e0, e1;                                      // raw emb row
  {
    const float* ar = emb + ((size_t)base + nodeBase + l15) * DIN + quad * 8;
    e0 = *(const float4*)ar;
    e1 = *(const float4*)(ar + 4);
  }
  __syncthreads();

  // ---- S1b: edge multiplicity count + gate-folded Af + score MFMA + A(0) ----
  bool rep = false;
  if (tid < NE) rep = (atomicAdd(&cells[ecell], 1u) == 0u);

  float gq[4];
  #pragma unroll
  for (int r = 0; r < 4; ++r) gq[r] = gateS[nodeBase + quad*4 + r];

  bf16x8 Af;                                          // gate pre-folded (row scaling)
  {
    const float gl = gateS[nodeBase + l15];
    Af[0]=(__bf16)(e0.x*gl); Af[1]=(__bf16)(e0.y*gl); Af[2]=(__bf16)(e0.z*gl); Af[3]=(__bf16)(e0.w*gl);
    Af[4]=(__bf16)(e1.x*gl); Af[5]=(__bf16)(e1.y*gl); Af[6]=(__bf16)(e1.z*gl); Af[7]=(__bf16)(e1.w*gl);
  }
  if (nh == 0) {                                      // scores: waves 0-3 only (no dup writes)
    bf16x8 Bs = *(const bf16x8*)(g_bs1F + lane*8);
    f32x4 ds = __builtin_amdgcn_mfma_f32_16x16x32_bf16(Af, Bs, zero4, 0, 0, 0);
    if (l15 < 8) {
      const float cc = g_c1s[l15];
      const int h = l15 >> 1;
      float* dstArr = (l15 & 1) ? &sS1d[h][0] : &sS1s[h][0];
      #pragma unroll
      for (int r = 0; r < 4; ++r) {
        int m = nodeBase + quad*4 + r;
        dstArr[m] = ds[r] + gq[r] * cc;               // gate already inside ds
      }
    }
  }
  // A(0): GEMM1 head 0 -> hT (4 Nt per wave: N-half split)
  #pragma unroll
  for (int Nt = 0; Nt < 4; ++Nt) {
    const int Ntg = nh*4 + Nt;
    const int n = Ntg*16 + l15;
    bf16x8 Bf = *(const bf16x8*)(g_w1F + ((0*8 + Ntg)*64 + lane)*8);
    f32x4 d = __builtin_amdgcn_mfma_f32_16x16x32_bf16(Af, Bf, zero4, 0, 0, 0);
    const float c1v = g_c1[0*Hd + n];
    bf16x4 hw;
    #pragma unroll
    for (int r = 0; r < 4; ++r) hw[r] = (__bf16)(d[r] + c1v * gq[r]);
    *(bf16x4*)(hT + n*NSTR + nodeBase + quad*4) = hw;
  }
  __syncthreads();

  // ---- P0: read multiplicity + scatter head-0 coeffs into Pbf[0] ----
  float fm = 0.f;
  if (tid < NE && rep) {
    fm = (float)cells[ecell];
    float e = sS1s[0][es] + sS1d[0][et];
    e = (e > 0.f) ? e : 0.2f * e;
    float pe = fm * __expf(e);
    Pbf[0][et*PROW + es] = (__bf16)pe;
    atomicAdd(SUMP(0, et), pe);
  }
  __syncthreads();                                    // cells dead; eluS free from here

  f32x4 acc[4];                                       // GEMM2 accumulators (N-half)
  #pragma unroll
  for (int i = 0; i < 4; ++i) acc[i] = zero4;
  f32x4 accS = zero4;                                 // layer-2 score accumulator (nh==0)

  #pragma unroll 1                                    // keep head loop rolled (R9)
  for (int hh = 0; hh < HEADS; ++hh) {
    const int cur = hh & 1;                           // buffer read by this C
    // ---- C(hh): out^T = hT @ P^T; 16-feature band per wave ----
    {
      bf16x8 Ac[2];
      #pragma unroll
      for (int Ks = 0; Ks < 2; ++Ks)
        Ac[Ks] = *(const bf16x8*)(hT + (m0 + l15)*NSTR + Ks*32 + quad*8);
      float4 b1v = *(const float4*)&b1[hh*Hd + m0 + quad*4];
      #pragma unroll
      for (int Nt = 0; Nt < 4; ++Nt) {
        bf16x8 B0f = *(const bf16x8*)(Pbf[cur] + (Nt*16 + l15)*PROW + quad*8);
        bf16x8 B1f = *(const bf16x8*)(Pbf[cur] + (Nt*16 + l15)*PROW + 32 + quad*8);
        const int t = Nt*16 + l15;
        const float si = RCP(*SUMP(cur, t) + 1e-16f);
        f32x4 d = __builtin_amdgcn_mfma_f32_16x16x32_bf16(Ac[0], B0f, zero4, 0, 0, 0);
        d = __builtin_amdgcn_mfma_f32_16x16x32_bf16(Ac[1], B1f, d, 0, 0, 0);
        bf16x4 w;
        #pragma unroll
        for (int r = 0; r < 4; ++r) {
          float hv = d[r]*si + b1v[r];
          hv = (hv > 0.f) ? hv : (__expf(hv) - 1.f);
          w[r] = (__bf16)hv;
        }
        *(bf16x4*)(eluS + t*EROW + m0 + quad*4) = w;
      }
    }
    if (hh >= 1) {                                    // zero buffer for NEXT scatter
      float4* p4 = (float4*)&Pbf[(hh+1)&1][0];        // 544 float4
      const float4 z4 = {0.f,0.f,0.f,0.f};
      p4[tid] = z4;
      if (tid < 32) p4[512 + tid] = z4;
    }
    __syncthreads();

    // ---- D(hh): GEMM2 (N-half per wave) + score col; stage next head or E ----
    #pragma unroll
    for (int Ks = 0; Ks < 4; ++Ks) {
      bf16x8 A2 = *(const bf16x8*)(eluS + (nodeBase + l15)*EROW + Ks*32 + quad*8);
      #pragma unroll
      for (int Nt = 0; Nt < 4; ++Nt) {
        const int Ntg = nh*4 + Nt;
        bf16x8 B2 = *(const bf16x8*)(g_w2F + (((hh*4 + Ks)*8 + Ntg)*64 + lane)*8);
        acc[Nt] = __builtin_amdgcn_mfma_f32_16x16x32_bf16(A2, B2, acc[Nt], 0, 0, 0);
      }
      if (nh == 0) {
        bf16x8 Bs2 = *(const bf16x8*)(g_wscF + ((hh*4 + Ks)*64 + lane)*8);
        accS = __builtin_amdgcn_mfma_f32_16x16x32_bf16(A2, Bs2, accS, 0, 0, 0);
      }
    }
    if (hh < 3) {                                     // A(hh+1): GEMM1 next head -> hT
      #pragma unroll
      for (int Nt = 0; Nt < 4; ++Nt) {
        const int Ntg = nh*4 + Nt;
        const int n = Ntg*16 + l15;
        bf16x8 Bf = *(const bf16x8*)(g_w1F + (((hh+1)*8 + Ntg)*64 + lane)*8);
        f32x4 d = __builtin_amdgcn_mfma_f32_16x16x32_bf16(Af, Bf, zero4, 0, 0, 0);
        const float c1v = g_c1[(hh+1)*Hd + n];
        bf16x4 hw;
        #pragma unroll
        for (int r = 0; r < 4; ++r) hw[r] = (__bf16)(d[r] + c1v * gq[r]);
        *(bf16x4*)(hT + n*NSTR + nodeBase + quad*4) = hw;
      }
      if (tid < NE && rep) {                          // scatter(hh+1) into zeroed buffer
        float e = sS1s[hh+1][es] + sS1d[hh+1][et];
        e = (e > 0.f) ? e : 0.2f * e;
        float pe = fm * __expf(e);
        Pbf[(hh+1)&1][et*PROW + es] = (__bf16)pe;
        atomicAdd(SUMP((hh+1)&1, et), pe);
      }
    } else {                                          // E: publish h2 -> hT, scores -> sSrc/sDst
      #pragma unroll
      for (int Nt = 0; Nt < 4; ++Nt) {
        const int n = (nh*4 + Nt)*16 + l15;
        bf16x4 hw;
        #pragma unroll
        for (int r = 0; r < 4; ++r) hw[r] = (__bf16)acc[Nt][r];
        *(bf16x4*)(hT + n*NSTR + nodeBase + quad*4) = hw;
      }
      if (nh == 0) {
        if (l15 == 0) {
          #pragma unroll
          for (int r = 0; r < 4; ++r) sSrc[nodeBase + quad*4 + r] = accS[r];
        } else if (l15 == 1) {
          #pragma unroll
          for (int r = 0; r < 4; ++r) sDst[nodeBase + quad*4 + r] = accS[r];
        }
      }
    }
    __syncthreads();
  }

  // ---- F: layer-2 edge scatter into Pbf[0] (zeroed in C(3)) ----
  if (tid < NE && rep) {
    float e = sSrc[es] + sDst[et];
    e = (e > 0.f) ? e : 0.2f * e;
    float pe = fm * __expf(e);
    Pbf[0][et*PROW + es] = (__bf16)pe;
    atomicAdd(SUMP(0, et), pe);
  }
  __syncthreads();

  // ---- W: w[s] = (1/64) * sum_t sInv_t * P2[t][s]; 8 threads/col ----
  {
    const int s_ = tid >> 3, part = tid & 7;
    float a = 0.f;
    #pragma unroll
    for (int q = 0; q < 8; ++q) {
      const int t = part*8 + q;
      a += RCP(*SUMP(0, t) + 1e-16f) * (float)Pbf[0][t*PROW + s_];
    }
    a += __shfl_xor(a, 1);
    a += __shfl_xor(a, 2);
    a += __shfl_xor(a, 4);
    if (part == 0) wS[s_] = (__bf16)(a * (1.f/64.f));
  }
  __syncthreads();

  // ---- G: gpool[f] = h2^T[f] · w + b2[f]; 16-feature band per wave ----
  {
    f32x4 d = zero4;
    #pragma unroll
    for (int Ks = 0; Ks < 2; ++Ks) {
      bf16x8 A = *(const bf16x8*)(hT + (m0 + l15)*NSTR + Ks*32 + quad*8);
      bf16x8 Bw = *(const bf16x8*)(wS + Ks*32 + quad*8);   // broadcast
      d = __builtin_amdgcn_mfma_f32_16x16x32_bf16(A, Bw, d, 0, 0, 0);
    }
    if (l15 == 0) {
      #pragma unroll
      for (int r = 0; r < 4; ++r) {
        const int f = m0 + quad*4 + r;
        gpool[f] = d[r] + b2[f];
      }
    }
  }
  __syncthreads();

  // ---- classifier layer 1: 8 threads/col ----
  {
    const int c = tid >> 3, p = tid & 7;
    float a = 0.f;
    #pragma unroll
    for (int i = 0; i < 16; ++i) {
      const int k = p*16 + i;
      a += gpool[k] * Wc1[k*Fn + c];
    }
    a += __shfl_xor(a, 1);
    a += __shfl_xor(a, 2);
    a += __shfl_xor(a, 4);
    if (p == 0) {
      a += bc1[c];
      hcS[c] = (a > 0.f) ? a : 0.01f * a;
    }
  }
  __syncthreads();

  // ---- classifier layer 2: 32 threads/col ----
  {
    const int c = tid >> 5, p = tid & 31;
    float a = 0.f;
    #pragma unroll
    for (int i = 0; i < 2; ++i) {
      const int k = p*2 + i;
      a += hcS[k] * Wc2[k*NC + c];
    }
    a += __shfl_xor(a, 1);
    a += __shfl_xor(a, 2);
    a += __shfl_xor(a, 4);
    a += __shfl_xor(a, 8);
    a += __shfl_xor(a, 16);
    if (p == 0) out[b*NC + c] = a + bc2[c];
  }
}
#undef SUMP
#undef RCP

extern "C" void kernel_launch(void* const* d_in, const int* in_sizes, int n_in,
                              void* d_out, int out_size, void* d_ws, size_t ws_size,
                              hipStream_t stream) {
  const float* emb = (const float*)d_in[0];
  const int*   ei  = (const int*)  d_in[1];
  // d_in[2] = batch_idx (layout known)
  const float* Wa  = (const float*)d_in[3];
  const float* ba  = (const float*)d_in[4];
  const float* gl  = (const float*)d_in[5];
  const float* W1  = (const float*)d_in[6];
  const float* as1 = (const float*)d_in[7];
  const float* ad1 = (const float*)d_in[8];
  const float* b1  = (const float*)d_in[9];
  const float* W2  = (const float*)d_in[10];
  const float* as2 = (const float*)d_in[11];
  const float* ad2 = (const float*)d_in[12];
  const float* b2  = (const float*)d_in[13];
  const float* Wc1 = (const float*)d_in[14];
  const float* bc1 = (const float*)d_in[15];
  const float* Wc2 = (const float*)d_in[16];
  const float* bc2 = (const float*)d_in[17];
  float* out = (float*)d_out;

  const int prep1N = DIN*W1C + W1C;                     // 16896
  hipLaunchKernelGGL(prep1, dim3((prep1N + BLK - 1)/BLK), dim3(BLK), 0, stream,
                     Wa, ba, W1);
  hipLaunchKernelGGL(prep2, dim3((P2_TOT + BLK - 1)/BLK), dim3(BLK), 0, stream,
                     W2, as1, ad1, as2, ad2);
  hipLaunchKernelGGL(gat_main, dim3(Bg), dim3(MBLK), 0, stream,
                     emb, ei, gl, b1, b2, Wc1, bc1, Wc2, bc2, out);
}

// Round 12
// 202.480 us; speedup vs baseline: 1.4519x; 1.4519x over previous
//
#include <hip/hip_runtime.h>
#include <math.h>

#define BLK 256   // prep kernels
#define MBLK 512  // gat_main: 8 waves

constexpr int Bg    = 2048;
constexpr int Fn    = 64;
constexpr int DIN   = 32;
constexpr int Hd    = 128;
constexpr int HEADS = 4;
constexpr int NC    = 16;
constexpr int EPG   = 128;
constexpr int Etot  = Bg * EPG;
constexpr int W1C   = HEADS * Hd;   // 512
constexpr int NSTR  = 68;           // hT row stride (bf16)
constexpr int EROW  = 132;          // eluS row stride
constexpr int PROW  = 68;           // Pbf row stride; row bytes [128,132) hold f32 softmax sum
constexpr int NE    = EPG + Fn;     // 192 edges incl self-loops

typedef __attribute__((ext_vector_type(8))) __bf16 bf16x8;
typedef __attribute__((ext_vector_type(4))) __bf16 bf16x4;
typedef __attribute__((ext_vector_type(4))) float  f32x4;

// ---- precomputed weights ----
__device__ __align__(16) __bf16 g_wcombT[W1C * DIN];
__device__ float g_c1[W1C];
__device__ float g_c1s[16];
__device__ __align__(16) __bf16 g_w1F[HEADS*8*64*8];        // 16384 elems
__device__ __align__(16) __bf16 g_w2F[HEADS*4*8*64*8];      // 65536 elems
__device__ __align__(16) __bf16 g_wscF[HEADS*4*64*8];       // 8192 elems
__device__ __align__(16) __bf16 g_bs1F[64*8];               // 512 elems

// ================= prep1: wcombT + c1 (R6-verified) =================
__global__ __launch_bounds__(BLK) void prep1(
    const float* __restrict__ Wa, const float* __restrict__ ba,
    const float* __restrict__ W1)
{
  __shared__ float WaS[DIN * Hd];                       // Wa transposed [m][k], 16 KB
  const int tid = threadIdx.x;
  for (int i = tid; i < DIN * Hd; i += BLK) {
    int k = i >> 7, m = i & 127;                        // coalesced read of Wa
    WaS[m * DIN + k] = Wa[i];
  }
  __syncthreads();

  int i = blockIdx.x * BLK + tid;
  if (i < DIN * W1C) {                                  // wcombT: i = n*32+k (coalesced write)
    int k = i & 31, n = i >> 5;
    float a0 = 0.f, a1 = 0.f, a2 = 0.f, a3 = 0.f;
    #pragma unroll
    for (int m = 0; m < Hd; m += 4) {
      a0 += WaS[(m  )*DIN + k] * W1[(m  )*W1C + n];
      a1 += WaS[(m+1)*DIN + k] * W1[(m+1)*W1C + n];
      a2 += WaS[(m+2)*DIN + k] * W1[(m+2)*W1C + n];
      a3 += WaS[(m+3)*DIN + k] * W1[(m+3)*W1C + n];
    }
    g_wcombT[i] = (__bf16)(a0 + a1 + a2 + a3);
  } else if (i < DIN*W1C + W1C) {                       // c1
    int n = i - DIN*W1C;
    float a0 = 0.f, a1 = 0.f, a2 = 0.f, a3 = 0.f;
    #pragma unroll
    for (int m = 0; m < Hd; m += 4) {
      a0 += ba[m  ] * W1[(m  )*W1C + n];
      a1 += ba[m+1] * W1[(m+1)*W1C + n];
      a2 += ba[m+2] * W1[(m+2)*W1C + n];
      a3 += ba[m+3] * W1[(m+3)*W1C + n];
    }
    g_c1[n] = a0 + a1 + a2 + a3;
  }
}

// ================= prep2: all fragment-major tables (R6-verified) =================
constexpr int R_W2F  = 65536;
constexpr int R_W1F  = 16384;
constexpr int R_WSCZ = 8192;
constexpr int R_WSCD = 4096;
constexpr int R_BS1Z = 512;
constexpr int R_BS1D = 1024;
constexpr int R_C1S  = 128;
constexpr int B0 = R_W2F;
constexpr int B1 = B0 + R_W1F;
constexpr int B2 = B1 + R_WSCZ;
constexpr int B3 = B2 + R_WSCD;
constexpr int B4 = B3 + R_BS1Z;
constexpr int B5 = B4 + R_BS1D;
constexpr int P2_TOT = B5 + R_C1S;                      // 95872

__global__ __launch_bounds__(BLK) void prep2(
    const float* __restrict__ W2,
    const float* __restrict__ as1, const float* __restrict__ ad1,
    const float* __restrict__ as2, const float* __restrict__ ad2)
{
  int i = blockIdx.x * BLK + threadIdx.x;
  if (i < B0) {                                         // w2F
    int k = i >> 7, n = i & 127;
    int hh = k >> 7, Ks = (k >> 5) & 3, q = (k >> 3) & 3, j = k & 7;
    int Nt = n >> 4, l = n & 15;
    int idx = (((hh*4 + Ks)*8 + Nt)*64 + (q*16 + l))*8 + j;
    g_w2F[idx] = (__bf16)W2[i];
  } else if (i < B1) {                                  // w1F
    int j = i - B0;
    int jj = j & 7, lane = (j >> 3) & 63, T = j >> 9;
    int hh = T >> 3, Nt = T & 7;
    int q = lane >> 4, l = lane & 15;
    g_w1F[j] = g_wcombT[(hh*Hd + Nt*16 + l)*DIN + q*8 + jj];
  } else if (i < B2) {                                  // wscF zero cells
    int j = i - B1;
    int lane = (j >> 3) & 63, c = lane & 15;
    if (c >= 2) g_wscF[j] = (__bf16)0.f;
  } else if (i < B3) {                                  // wscF dots
    int j = i - B2;
    int p = j & 3, c = (j >> 2) & 1, k = j >> 3;
    const float* av = c ? ad2 : as2;
    float a0 = 0.f, a1 = 0.f, a2 = 0.f, a3 = 0.f;
    #pragma unroll
    for (int q = 0; q < 32; q += 4) {
      int f = p*32 + q;
      a0 += W2[(size_t)k*Hd + f    ] * av[f    ];
      a1 += W2[(size_t)k*Hd + f + 1] * av[f + 1];
      a2 += W2[(size_t)k*Hd + f + 2] * av[f + 2];
      a3 += W2[(size_t)k*Hd + f + 3] * av[f + 3];
    }
    float a = a0 + a1 + a2 + a3;
    a += __shfl_xor(a, 1);
    a += __shfl_xor(a, 2);
    if (p == 0) {
      int T = k >> 5, q2 = (k >> 3) & 3, jj = k & 7;
      g_wscF[(T*64 + q2*16 + c)*8 + jj] = (__bf16)a;
    }
  } else if (i < B4) {                                  // bs1F zero cells
    int j = i - B3;
    int lane = j >> 3, c = lane & 15;
    if (c >= 8) g_bs1F[j] = (__bf16)0.f;
  } else if (i < B5) {                                  // bs1F dots
    int j = i - B4;
    int p = j & 3, c = (j >> 2) & 7, kk = j >> 5;
    int h = c >> 1;
    const float* av = (c & 1) ? (ad1 + h*Hd) : (as1 + h*Hd);
    float a0 = 0.f, a1 = 0.f, a2 = 0.f, a3 = 0.f;
    #pragma unroll
    for (int q = 0; q < 32; q += 4) {
      int f = p*32 + q;
      a0 += (float)g_wcombT[(h*Hd + f    )*DIN + kk] * av[f    ];
      a1 += (float)g_wcombT[(h*Hd + f + 1)*DIN + kk] * av[f + 1];
      a2 += (float)g_wcombT[(h*Hd + f + 2)*DIN + kk] * av[f + 2];
      a3 += (float)g_wcombT[(h*Hd + f + 3)*DIN + kk] * av[f + 3];
    }
    float a = a0 + a1 + a2 + a3;
    a += __shfl_xor(a, 1);
    a += __shfl_xor(a, 2);
    if (p == 0) {
      int q2 = kk >> 3, jj = kk & 7;
      g_bs1F[(q2*16 + c)*8 + jj] = (__bf16)a;
    }
  } else if (i < P2_TOT) {                              // c1s
    int j = i - B5;
    int p = j & 7, c = j >> 3;
    float a = 0.f;
    if (c < 8) {
      int h = c >> 1;
      const float* av = (c & 1) ? (ad1 + h*Hd) : (as1 + h*Hd);
      #pragma unroll
      for (int q = 0; q < 16; ++q) {
        int f = p*16 + q;
        a += g_c1[h*Hd + f] * av[f];
      }
    }
    a += __shfl_xor(a, 1);
    a += __shfl_xor(a, 2);
    a += __shfl_xor(a, 4);
    if (p == 0) g_c1s[c] = a;
  }
}

// ================= main fused kernel: 8-WAVE variant =================
// R11: (512,6) squeezed the allocator to 40 VGPR -> 322MB/block scratch
// spill (same failure as R2). Fix = R3's fix: (512,4) gives a 128-reg
// budget (no spill); actual alloc ~64 still permits the LDS-limited
// 3 blocks/CU = 24 waves/CU. Experiment otherwise unchanged: 512 thr,
// half-length per-wave chains, same LDS map (53760B).
#define SUMP(buf, t) ((float*)((char*)&Pbf[buf][(t)*PROW] + 128))
#define RCP(x) __builtin_amdgcn_rcpf(x)
__global__ __launch_bounds__(MBLK, 4) void gat_main(
    const float* __restrict__ emb, const int* __restrict__ ei,
    const float* __restrict__ gate_logits,
    const float* __restrict__ b1, const float* __restrict__ b2,
    const float* __restrict__ Wc1, const float* __restrict__ bc1,
    const float* __restrict__ Wc2, const float* __restrict__ bc2,
    float* __restrict__ out)
{
  __shared__ __align__(16) __bf16 hT[Hd * NSTR];      // 17408: h^T [feature][node]
  __shared__ __align__(16) __bf16 eluS[Fn * EROW];    // 16896: elu [node][feat]; cells+gateS alias
  __shared__ __align__(16) __bf16 Pbf[2][Fn * PROW];  // 17408: P dbuf; padding = sums; [1] = tail
  __shared__ float sS1s[HEADS][Fn], sS1d[HEADS][Fn];  // 2048: layer-1 scores

  unsigned* cells = (unsigned*)eluS;                  // bytes [0,16384) of eluS (setup only)
  float*   gateS  = (float*)(eluS + 8192);            // bytes [16384,16640) of eluS
  float*   sSrc   = (float*)&Pbf[1][0];               // tail aliases (Pbf[1] dead after C(3))
  float*   sDst   = sSrc + Fn;
  __bf16*  wS     = (__bf16*)(sDst + Fn);             // byte 512 in Pbf[1]: 16-aligned
  float*   gpool  = (float*)(wS + Fn);
  float*   hcS    = gpool + Hd;

  const int b    = blockIdx.x;
  const int tid  = threadIdx.x;
  const int lane = tid & 63;
  const int wv   = tid >> 6;          // 0..7
  const int ng   = wv & 3;            // node group (16 nodes)
  const int nh   = wv >> 2;           // N-half (0/1)
  const int quad = lane >> 4;
  const int l15  = lane & 15;
  const int nodeBase = ng * 16;
  const int m0   = wv * 16;           // 16-feature band for C/G
  const int base = b * Fn;

  const f32x4 zero4 = {0.f, 0.f, 0.f, 0.f};

  // ---- S1a: zero cells + both Pbf buffers (incl padded sums), gate, edges, emb ----
  int es = 0, et = 0, ecell = 0;
  if (tid < NE) {
    if (tid < EPG) {
      es = ei[(size_t)b*EPG + tid] - base;
      et = ei[(size_t)Etot + (size_t)b*EPG + tid] - base;
    } else {
      es = et = tid - EPG;
    }
    ecell = et * Fn + es;
  }
  {
    float4* c4 = (float4*)cells;                      // 16384B = 1024 float4
    const float4 z4 = {0.f,0.f,0.f,0.f};
    c4[tid] = z4; c4[tid + 512] = z4;
  }
  {
    float4* p4 = (float4*)&Pbf[0][0];                 // 2*8704B = 1088 float4
    const float4 z4 = {0.f,0.f,0.f,0.f};
    p4[tid] = z4; p4[tid + 512] = z4;                 // 0..1023
    if (tid < 64) p4[1024 + tid] = z4;                // 1024..1087
  }
  if (tid < Fn) {
    float g = 1.f / (1.f + expf(-gate_logits[tid]));
    gateS[tid] = g;
    if (b == 0) out[Bg*NC + tid] = g;                 // second tuple output (gate)
  }
  float4 e0, e1;                                      // raw emb row
  {
    const float* ar = emb + ((size_t)base + nodeBase + l15) * DIN + quad * 8;
    e0 = *(const float4*)ar;
    e1 = *(const float4*)(ar + 4);
  }
  __syncthreads();

  // ---- S1b: edge multiplicity count + gate-folded Af + score MFMA + A(0) ----
  bool rep = false;
  if (tid < NE) rep = (atomicAdd(&cells[ecell], 1u) == 0u);

  float gq[4];
  #pragma unroll
  for (int r = 0; r < 4; ++r) gq[r] = gateS[nodeBase + quad*4 + r];

  bf16x8 Af;                                          // gate pre-folded (row scaling)
  {
    const float gl = gateS[nodeBase + l15];
    Af[0]=(__bf16)(e0.x*gl); Af[1]=(__bf16)(e0.y*gl); Af[2]=(__bf16)(e0.z*gl); Af[3]=(__bf16)(e0.w*gl);
    Af[4]=(__bf16)(e1.x*gl); Af[5]=(__bf16)(e1.y*gl); Af[6]=(__bf16)(e1.z*gl); Af[7]=(__bf16)(e1.w*gl);
  }
  if (nh == 0) {                                      // scores: waves 0-3 only (no dup writes)
    bf16x8 Bs = *(const bf16x8*)(g_bs1F + lane*8);
    f32x4 ds = __builtin_amdgcn_mfma_f32_16x16x32_bf16(Af, Bs, zero4, 0, 0, 0);
    if (l15 < 8) {
      const float cc = g_c1s[l15];
      const int h = l15 >> 1;
      float* dstArr = (l15 & 1) ? &sS1d[h][0] : &sS1s[h][0];
      #pragma unroll
      for (int r = 0; r < 4; ++r) {
        int m = nodeBase + quad*4 + r;
        dstArr[m] = ds[r] + gq[r] * cc;               // gate already inside ds
      }
    }
  }
  // A(0): GEMM1 head 0 -> hT (4 Nt per wave: N-half split)
  #pragma unroll
  for (int Nt = 0; Nt < 4; ++Nt) {
    const int Ntg = nh*4 + Nt;
    const int n = Ntg*16 + l15;
    bf16x8 Bf = *(const bf16x8*)(g_w1F + ((0*8 + Ntg)*64 + lane)*8);
    f32x4 d = __builtin_amdgcn_mfma_f32_16x16x32_bf16(Af, Bf, zero4, 0, 0, 0);
    const float c1v = g_c1[0*Hd + n];
    bf16x4 hw;
    #pragma unroll
    for (int r = 0; r < 4; ++r) hw[r] = (__bf16)(d[r] + c1v * gq[r]);
    *(bf16x4*)(hT + n*NSTR + nodeBase + quad*4) = hw;
  }
  __syncthreads();

  // ---- P0: read multiplicity + scatter head-0 coeffs into Pbf[0] ----
  float fm = 0.f;
  if (tid < NE && rep) {
    fm = (float)cells[ecell];
    float e = sS1s[0][es] + sS1d[0][et];
    e = (e > 0.f) ? e : 0.2f * e;
    float pe = fm * __expf(e);
    Pbf[0][et*PROW + es] = (__bf16)pe;
    atomicAdd(SUMP(0, et), pe);
  }
  __syncthreads();                                    // cells dead; eluS free from here

  f32x4 acc[4];                                       // GEMM2 accumulators (N-half)
  #pragma unroll
  for (int i = 0; i < 4; ++i) acc[i] = zero4;
  f32x4 accS = zero4;                                 // layer-2 score accumulator (nh==0)

  #pragma unroll 1                                    // keep head loop rolled (R9)
  for (int hh = 0; hh < HEADS; ++hh) {
    const int cur = hh & 1;                           // buffer read by this C
    // ---- C(hh): out^T = hT @ P^T; 16-feature band per wave ----
    {
      bf16x8 Ac[2];
      #pragma unroll
      for (int Ks = 0; Ks < 2; ++Ks)
        Ac[Ks] = *(const bf16x8*)(hT + (m0 + l15)*NSTR + Ks*32 + quad*8);
      float4 b1v = *(const float4*)&b1[hh*Hd + m0 + quad*4];
      #pragma unroll
      for (int Nt = 0; Nt < 4; ++Nt) {
        bf16x8 B0f = *(const bf16x8*)(Pbf[cur] + (Nt*16 + l15)*PROW + quad*8);
        bf16x8 B1f = *(const bf16x8*)(Pbf[cur] + (Nt*16 + l15)*PROW + 32 + quad*8);
        const int t = Nt*16 + l15;
        const float si = RCP(*SUMP(cur, t) + 1e-16f);
        f32x4 d = __builtin_amdgcn_mfma_f32_16x16x32_bf16(Ac[0], B0f, zero4, 0, 0, 0);
        d = __builtin_amdgcn_mfma_f32_16x16x32_bf16(Ac[1], B1f, d, 0, 0, 0);
        bf16x4 w;
        #pragma unroll
        for (int r = 0; r < 4; ++r) {
          float hv = d[r]*si + b1v[r];
          hv = (hv > 0.f) ? hv : (__expf(hv) - 1.f);
          w[r] = (__bf16)hv;
        }
        *(bf16x4*)(eluS + t*EROW + m0 + quad*4) = w;
      }
    }
    if (hh >= 1) {                                    // zero buffer for NEXT scatter
      float4* p4 = (float4*)&Pbf[(hh+1)&1][0];        // 544 float4
      const float4 z4 = {0.f,0.f,0.f,0.f};
      p4[tid] = z4;
      if (tid < 32) p4[512 + tid] = z4;
    }
    __syncthreads();

    // ---- D(hh): GEMM2 (N-half per wave) + score col; stage next head or E ----
    #pragma unroll
    for (int Ks = 0; Ks < 4; ++Ks) {
      bf16x8 A2 = *(const bf16x8*)(eluS + (nodeBase + l15)*EROW + Ks*32 + quad*8);
      #pragma unroll
      for (int Nt = 0; Nt < 4; ++Nt) {
        const int Ntg = nh*4 + Nt;
        bf16x8 B2 = *(const bf16x8*)(g_w2F + (((hh*4 + Ks)*8 + Ntg)*64 + lane)*8);
        acc[Nt] = __builtin_amdgcn_mfma_f32_16x16x32_bf16(A2, B2, acc[Nt], 0, 0, 0);
      }
      if (nh == 0) {
        bf16x8 Bs2 = *(const bf16x8*)(g_wscF + ((hh*4 + Ks)*64 + lane)*8);
        accS = __builtin_amdgcn_mfma_f32_16x16x32_bf16(A2, Bs2, accS, 0, 0, 0);
      }
    }
    if (hh < 3) {                                     // A(hh+1): GEMM1 next head -> hT
      #pragma unroll
      for (int Nt = 0; Nt < 4; ++Nt) {
        const int Ntg = nh*4 + Nt;
        const int n = Ntg*16 + l15;
        bf16x8 Bf = *(const bf16x8*)(g_w1F + (((hh+1)*8 + Ntg)*64 + lane)*8);
        f32x4 d = __builtin_amdgcn_mfma_f32_16x16x32_bf16(Af, Bf, zero4, 0, 0, 0);
        const float c1v = g_c1[(hh+1)*Hd + n];
        bf16x4 hw;
        #pragma unroll
        for (int r = 0; r < 4; ++r) hw[r] = (__bf16)(d[r] + c1v * gq[r]);
        *(bf16x4*)(hT + n*NSTR + nodeBase + quad*4) = hw;
      }
      if (tid < NE && rep) {                          // scatter(hh+1) into zeroed buffer
        float e = sS1s[hh+1][es] + sS1d[hh+1][et];
        e = (e > 0.f) ? e : 0.2f * e;
        float pe = fm * __expf(e);
        Pbf[(hh+1)&1][et*PROW + es] = (__bf16)pe;
        atomicAdd(SUMP((hh+1)&1, et), pe);
      }
    } else {                                          // E: publish h2 -> hT, scores -> sSrc/sDst
      #pragma unroll
      for (int Nt = 0; Nt < 4; ++Nt) {
        const int n = (nh*4 + Nt)*16 + l15;
        bf16x4 hw;
        #pragma unroll
        for (int r = 0; r < 4; ++r) hw[r] = (__bf16)acc[Nt][r];
        *(bf16x4*)(hT + n*NSTR + nodeBase + quad*4) = hw;
      }
      if (nh == 0) {
        if (l15 == 0) {
          #pragma unroll
          for (int r = 0; r < 4; ++r) sSrc[nodeBase + quad*4 + r] = accS[r];
        } else if (l15 == 1) {
          #pragma unroll
          for (int r = 0; r < 4; ++r) sDst[nodeBase + quad*4 + r] = accS[r];
        }
      }
    }
    __syncthreads();
  }

  // ---- F: layer-2 edge scatter into Pbf[0] (zeroed in C(3)) ----
  if (tid < NE && rep) {
    float e = sSrc[es] + sDst[et];
    e = (e > 0.f) ? e : 0.2f * e;
    float pe = fm * __expf(e);
    Pbf[0][et*PROW + es] = (__bf16)pe;
    atomicAdd(SUMP(0, et), pe);
  }
  __syncthreads();

  // ---- W: w[s] = (1/64) * sum_t sInv_t * P2[t][s]; 8 threads/col ----
  {
    const int s_ = tid >> 3, part = tid & 7;
    float a = 0.f;
    #pragma unroll
    for (int q = 0; q < 8; ++q) {
      const int t = part*8 + q;
      a += RCP(*SUMP(0, t) + 1e-16f) * (float)Pbf[0][t*PROW + s_];
    }
    a += __shfl_xor(a, 1);
    a += __shfl_xor(a, 2);
    a += __shfl_xor(a, 4);
    if (part == 0) wS[s_] = (__bf16)(a * (1.f/64.f));
  }
  __syncthreads();

  // ---- G: gpool[f] = h2^T[f] · w + b2[f]; 16-feature band per wave ----
  {
    f32x4 d = zero4;
    #pragma unroll
    for (int Ks = 0; Ks < 2; ++Ks) {
      bf16x8 A = *(const bf16x8*)(hT + (m0 + l15)*NSTR + Ks*32 + quad*8);
      bf16x8 Bw = *(const bf16x8*)(wS + Ks*32 + quad*8);   // broadcast
      d = __builtin_amdgcn_mfma_f32_16x16x32_bf16(A, Bw, d, 0, 0, 0);
    }
    if (l15 == 0) {
      #pragma unroll
      for (int r = 0; r < 4; ++r) {
        const int f = m0 + quad*4 + r;
        gpool[f] = d[r] + b2[f];
      }
    }
  }
  __syncthreads();

  // ---- classifier layer 1: 8 threads/col ----
  {
    const int c = tid >> 3, p = tid & 7;
    float a = 0.f;
    #pragma unroll
    for (int i = 0; i < 16; ++i) {
      const int k = p*16 + i;
      a += gpool[k] * Wc1[k*Fn + c];
    }
    a += __shfl_xor(a, 1);
    a += __shfl_xor(a, 2);
    a += __shfl_xor(a, 4);
    if (p == 0) {
      a += bc1[c];
      hcS[c] = (a > 0.f) ? a : 0.01f * a;
    }
  }
  __syncthreads();

  // ---- classifier layer 2: 32 threads/col ----
  {
    const int c = tid >> 5, p = tid & 31;
    float a = 0.f;
    #pragma unroll
    for (int i = 0; i < 2; ++i) {
      const int k = p*2 + i;
      a += hcS[k] * Wc2[k*NC + c];
    }
    a += __shfl_xor(a, 1);
    a += __shfl_xor(a, 2);
    a += __shfl_xor(a, 4);
    a += __shfl_xor(a, 8);
    a += __shfl_xor(a, 16);
    if (p == 0) out[b*NC + c] = a + bc2[c];
  }
}
#undef SUMP
#undef RCP

extern "C" void kernel_launch(void* const* d_in, const int* in_sizes, int n_in,
                              void* d_out, int out_size, void* d_ws, size_t ws_size,
                              hipStream_t stream) {
  const float* emb = (const float*)d_in[0];
  const int*   ei  = (const int*)  d_in[1];
  // d_in[2] = batch_idx (layout known)
  const float* Wa  = (const float*)d_in[3];
  const float* ba  = (const float*)d_in[4];
  const float* gl  = (const float*)d_in[5];
  const float* W1  = (const float*)d_in[6];
  const float* as1 = (const float*)d_in[7];
  const float* ad1 = (const float*)d_in[8];
  const float* b1  = (const float*)d_in[9];
  const float* W2  = (const float*)d_in[10];
  const float* as2 = (const float*)d_in[11];
  const float* ad2 = (const float*)d_in[12];
  const float* b2  = (const float*)d_in[13];
  const float* Wc1 = (const float*)d_in[14];
  const float* bc1 = (const float*)d_in[15];
  const float* Wc2 = (const float*)d_in[16];
  const float* bc2 = (const float*)d_in[17];
  float* out = (float*)d_out;

  const int prep1N = DIN*W1C + W1C;                     // 16896
  hipLaunchKernelGGL(prep1, dim3((prep1N + BLK - 1)/BLK), dim3(BLK), 0, stream,
                     Wa, ba, W1);
  hipLaunchKernelGGL(prep2, dim3((P2_TOT + BLK - 1)/BLK), dim3(BLK), 0, stream,
                     W2, as1, ad1, as2, ad2);
  hipLaunchKernelGGL(gat_main, dim3(Bg), dim3(MBLK), 0, stream,
                     emb, ei, gl, b1, b2, Wc1, bc1, Wc2, bc2, out);
}

// Round 13
// 187.383 us; speedup vs baseline: 1.5689x; 1.0806x over previous
//
#include <hip/hip_runtime.h>
#include <math.h>

#define BLK 256

constexpr int Bg    = 2048;
constexpr int Fn    = 64;
constexpr int DIN   = 32;
constexpr int Hd    = 128;
constexpr int HEADS = 4;
constexpr int NC    = 16;
constexpr int EPG   = 128;
constexpr int Etot  = Bg * EPG;
constexpr int W1C   = HEADS * Hd;   // 512
constexpr int NSTR  = 68;           // hT row stride (bf16)
constexpr int EROW  = 132;          // eluS row stride
constexpr int PROW  = 68;           // Pbf row stride; row bytes [128,132) hold f32 softmax sum
constexpr int NE    = EPG + Fn;     // 192 edges incl self-loops

typedef __attribute__((ext_vector_type(8))) __bf16 bf16x8;
typedef __attribute__((ext_vector_type(4))) __bf16 bf16x4;
typedef __attribute__((ext_vector_type(4))) float  f32x4;

// ---- precomputed weights ----
__device__ __align__(16) __bf16 g_wcombT[W1C * DIN];
__device__ float g_c1[W1C];
__device__ float g_c1s[16];
__device__ __align__(16) __bf16 g_w1F[HEADS*8*64*8];        // 16384 elems
__device__ __align__(16) __bf16 g_w2F[HEADS*4*8*64*8];      // 65536 elems
__device__ __align__(16) __bf16 g_wscF[HEADS*4*64*8];       // 8192 elems
__device__ __align__(16) __bf16 g_bs1F[64*8];               // 512 elems

// ================= prep1: wcombT + c1 (R6-verified) =================
__global__ __launch_bounds__(BLK) void prep1(
    const float* __restrict__ Wa, const float* __restrict__ ba,
    const float* __restrict__ W1)
{
  __shared__ float WaS[DIN * Hd];                       // Wa transposed [m][k], 16 KB
  const int tid = threadIdx.x;
  for (int i = tid; i < DIN * Hd; i += BLK) {
    int k = i >> 7, m = i & 127;                        // coalesced read of Wa
    WaS[m * DIN + k] = Wa[i];
  }
  __syncthreads();

  int i = blockIdx.x * BLK + tid;
  if (i < DIN * W1C) {                                  // wcombT: i = n*32+k (coalesced write)
    int k = i & 31, n = i >> 5;
    float a0 = 0.f, a1 = 0.f, a2 = 0.f, a3 = 0.f;
    #pragma unroll
    for (int m = 0; m < Hd; m += 4) {
      a0 += WaS[(m  )*DIN + k] * W1[(m  )*W1C + n];
      a1 += WaS[(m+1)*DIN + k] * W1[(m+1)*W1C + n];
      a2 += WaS[(m+2)*DIN + k] * W1[(m+2)*W1C + n];
      a3 += WaS[(m+3)*DIN + k] * W1[(m+3)*W1C + n];
    }
    g_wcombT[i] = (__bf16)(a0 + a1 + a2 + a3);
  } else if (i < DIN*W1C + W1C) {                       // c1
    int n = i - DIN*W1C;
    float a0 = 0.f, a1 = 0.f, a2 = 0.f, a3 = 0.f;
    #pragma unroll
    for (int m = 0; m < Hd; m += 4) {
      a0 += ba[m  ] * W1[(m  )*W1C + n];
      a1 += ba[m+1] * W1[(m+1)*W1C + n];
      a2 += ba[m+2] * W1[(m+2)*W1C + n];
      a3 += ba[m+3] * W1[(m+3)*W1C + n];
    }
    g_c1[n] = a0 + a1 + a2 + a3;
  }
}

// ================= prep2: all fragment-major tables (R6-verified) =================
constexpr int R_W2F  = 65536;
constexpr int R_W1F  = 16384;
constexpr int R_WSCZ = 8192;
constexpr int R_WSCD = 4096;
constexpr int R_BS1Z = 512;
constexpr int R_BS1D = 1024;
constexpr int R_C1S  = 128;
constexpr int B0 = R_W2F;
constexpr int B1 = B0 + R_W1F;
constexpr int B2 = B1 + R_WSCZ;
constexpr int B3 = B2 + R_WSCD;
constexpr int B4 = B3 + R_BS1Z;
constexpr int B5 = B4 + R_BS1D;
constexpr int P2_TOT = B5 + R_C1S;                      // 95872

__global__ __launch_bounds__(BLK) void prep2(
    const float* __restrict__ W2,
    const float* __restrict__ as1, const float* __restrict__ ad1,
    const float* __restrict__ as2, const float* __restrict__ ad2)
{
  int i = blockIdx.x * BLK + threadIdx.x;
  if (i < B0) {                                         // w2F
    int k = i >> 7, n = i & 127;
    int hh = k >> 7, Ks = (k >> 5) & 3, q = (k >> 3) & 3, j = k & 7;
    int Nt = n >> 4, l = n & 15;
    int idx = (((hh*4 + Ks)*8 + Nt)*64 + (q*16 + l))*8 + j;
    g_w2F[idx] = (__bf16)W2[i];
  } else if (i < B1) {                                  // w1F
    int j = i - B0;
    int jj = j & 7, lane = (j >> 3) & 63, T = j >> 9;
    int hh = T >> 3, Nt = T & 7;
    int q = lane >> 4, l = lane & 15;
    g_w1F[j] = g_wcombT[(hh*Hd + Nt*16 + l)*DIN + q*8 + jj];
  } else if (i < B2) {                                  // wscF zero cells
    int j = i - B1;
    int lane = (j >> 3) & 63, c = lane & 15;
    if (c >= 2) g_wscF[j] = (__bf16)0.f;
  } else if (i < B3) {                                  // wscF dots
    int j = i - B2;
    int p = j & 3, c = (j >> 2) & 1, k = j >> 3;
    const float* av = c ? ad2 : as2;
    float a0 = 0.f, a1 = 0.f, a2 = 0.f, a3 = 0.f;
    #pragma unroll
    for (int q = 0; q < 32; q += 4) {
      int f = p*32 + q;
      a0 += W2[(size_t)k*Hd + f    ] * av[f    ];
      a1 += W2[(size_t)k*Hd + f + 1] * av[f + 1];
      a2 += W2[(size_t)k*Hd + f + 2] * av[f + 2];
      a3 += W2[(size_t)k*Hd + f + 3] * av[f + 3];
    }
    float a = a0 + a1 + a2 + a3;
    a += __shfl_xor(a, 1);
    a += __shfl_xor(a, 2);
    if (p == 0) {
      int T = k >> 5, q2 = (k >> 3) & 3, jj = k & 7;
      g_wscF[(T*64 + q2*16 + c)*8 + jj] = (__bf16)a;
    }
  } else if (i < B4) {                                  // bs1F zero cells
    int j = i - B3;
    int lane = j >> 3, c = lane & 15;
    if (c >= 8) g_bs1F[j] = (__bf16)0.f;
  } else if (i < B5) {                                  // bs1F dots
    int j = i - B4;
    int p = j & 3, c = (j >> 2) & 7, kk = j >> 5;
    int h = c >> 1;
    const float* av = (c & 1) ? (ad1 + h*Hd) : (as1 + h*Hd);
    float a0 = 0.f, a1 = 0.f, a2 = 0.f, a3 = 0.f;
    #pragma unroll
    for (int q = 0; q < 32; q += 4) {
      int f = p*32 + q;
      a0 += (float)g_wcombT[(h*Hd + f    )*DIN + kk] * av[f    ];
      a1 += (float)g_wcombT[(h*Hd + f + 1)*DIN + kk] * av[f + 1];
      a2 += (float)g_wcombT[(h*Hd + f + 2)*DIN + kk] * av[f + 2];
      a3 += (float)g_wcombT[(h*Hd + f + 3)*DIN + kk] * av[f + 3];
    }
    float a = a0 + a1 + a2 + a3;
    a += __shfl_xor(a, 1);
    a += __shfl_xor(a, 2);
    if (p == 0) {
      int q2 = kk >> 3, jj = kk & 7;
      g_bs1F[(q2*16 + c)*8 + jj] = (__bf16)a;
    }
  } else if (i < P2_TOT) {                              // c1s
    int j = i - B5;
    int p = j & 7, c = j >> 3;
    float a = 0.f;
    if (c < 8) {
      int h = c >> 1;
      const float* av = (c & 1) ? (ad1 + h*Hd) : (as1 + h*Hd);
      #pragma unroll
      for (int q = 0; q < 16; ++q) {
        int f = p*16 + q;
        a += g_c1[h*Hd + f] * av[f];
      }
    }
    a += __shfl_xor(a, 1);
    a += __shfl_xor(a, 2);
    a += __shfl_xor(a, 4);
    if (p == 0) g_c1s[c] = a;
  }
}

// ================= main fused kernel =================
// Occupancy axis CLOSED (R3/R9/R12: 16 and 24 waves/CU both worse than 12).
// Base = R9 best (256thr, 3 blk/CU, rolled hh loop, rcp: 97.2us).
// THIS ROUND (single variable): wave-0-only barrier-free tail. After F's
// barrier, waves 1-3 return; wave 0 computes W+G+cls1+cls2 with in-wave
// ordering only. Removes 3 __syncthreads + retires 3/4 of block early.
#define SUMP(buf, t) ((float*)((char*)&Pbf[buf][(t)*PROW] + 128))
#define RCP(x) __builtin_amdgcn_rcpf(x)
__global__ __launch_bounds__(BLK, 3) void gat_main(
    const float* __restrict__ emb, const int* __restrict__ ei,
    const float* __restrict__ gate_logits,
    const float* __restrict__ b1, const float* __restrict__ b2,
    const float* __restrict__ Wc1, const float* __restrict__ bc1,
    const float* __restrict__ Wc2, const float* __restrict__ bc2,
    float* __restrict__ out)
{
  __shared__ __align__(16) __bf16 hT[Hd * NSTR];      // 17408: h^T [feature][node]
  __shared__ __align__(16) __bf16 eluS[Fn * EROW];    // 16896: elu [node][feat]; cells+gateS alias
  __shared__ __align__(16) __bf16 Pbf[2][Fn * PROW];  // 17408: P dbuf; padding = sums; [1] = tail
  __shared__ float sS1s[HEADS][Fn], sS1d[HEADS][Fn];  // 2048: layer-1 scores

  unsigned* cells = (unsigned*)eluS;                  // bytes [0,16384) of eluS (setup only)
  float*   gateS  = (float*)(eluS + 8192);            // bytes [16384,16640) of eluS
  float*   sSrc   = (float*)&Pbf[1][0];               // tail aliases (Pbf[1] dead after C(3))
  float*   sDst   = sSrc + Fn;
  __bf16*  wS     = (__bf16*)(sDst + Fn);             // byte 512 in Pbf[1]: 16-aligned
  float*   gpool  = (float*)(wS + Fn);
  float*   hcS    = gpool + Hd;

  const int b    = blockIdx.x;
  const int tid  = threadIdx.x;
  const int lane = tid & 63;
  const int wv   = tid >> 6;
  const int quad = lane >> 4;
  const int l15  = lane & 15;
  const int nodeBase = wv * 16;
  const int m0   = wv * 32;
  const int base = b * Fn;

  const f32x4 zero4 = {0.f, 0.f, 0.f, 0.f};

  // ---- S1a: zero cells + both Pbf buffers (incl padded sums), gate, edges, emb ----
  int es = 0, et = 0, ecell = 0;
  if (tid < NE) {
    if (tid < EPG) {
      es = ei[(size_t)b*EPG + tid] - base;
      et = ei[(size_t)Etot + (size_t)b*EPG + tid] - base;
    } else {
      es = et = tid - EPG;
    }
    ecell = et * Fn + es;
  }
  {
    float4* c4 = (float4*)cells;                      // 16384B = 1024 float4
    const float4 z4 = {0.f,0.f,0.f,0.f};
    c4[tid] = z4; c4[tid + 256] = z4; c4[tid + 512] = z4; c4[tid + 768] = z4;
  }
  {
    float4* p4 = (float4*)&Pbf[0][0];                 // 2*8704B = 1088 float4
    const float4 z4 = {0.f,0.f,0.f,0.f};
    #pragma unroll
    for (int k = 0; k < 4; ++k) p4[tid + k*BLK] = z4;
    if (tid < 64) p4[1024 + tid] = z4;
  }
  if (tid < Fn) {
    float g = 1.f / (1.f + expf(-gate_logits[tid]));
    gateS[tid] = g;
    if (b == 0) out[Bg*NC + tid] = g;                 // second tuple output (gate)
  }
  float4 e0, e1;                                      // raw emb row
  {
    const float* ar = emb + ((size_t)base + nodeBase + l15) * DIN + quad * 8;
    e0 = *(const float4*)ar;
    e1 = *(const float4*)(ar + 4);
  }
  __syncthreads();

  // ---- S1b: edge multiplicity count + gate-folded Af + score MFMA + A(0) ----
  bool rep = false;
  if (tid < NE) rep = (atomicAdd(&cells[ecell], 1u) == 0u);

  float gq[4];
  #pragma unroll
  for (int r = 0; r < 4; ++r) gq[r] = gateS[nodeBase + quad*4 + r];

  bf16x8 Af;                                          // gate pre-folded (row scaling)
  {
    const float gl = gateS[nodeBase + l15];
    Af[0]=(__bf16)(e0.x*gl); Af[1]=(__bf16)(e0.y*gl); Af[2]=(__bf16)(e0.z*gl); Af[3]=(__bf16)(e0.w*gl);
    Af[4]=(__bf16)(e1.x*gl); Af[5]=(__bf16)(e1.y*gl); Af[6]=(__bf16)(e1.z*gl); Af[7]=(__bf16)(e1.w*gl);
  }
  {
    bf16x8 Bs = *(const bf16x8*)(g_bs1F + lane*8);
    f32x4 ds = __builtin_amdgcn_mfma_f32_16x16x32_bf16(Af, Bs, zero4, 0, 0, 0);
    if (l15 < 8) {
      const float cc = g_c1s[l15];
      const int h = l15 >> 1;
      float* dstArr = (l15 & 1) ? &sS1d[h][0] : &sS1s[h][0];
      #pragma unroll
      for (int r = 0; r < 4; ++r) {
        int m = nodeBase + quad*4 + r;
        dstArr[m] = ds[r] + gq[r] * cc;               // gate already inside ds
      }
    }
  }
  // A(0): GEMM1 head 0 -> hT
  #pragma unroll
  for (int Nt = 0; Nt < 8; ++Nt) {
    const int n = Nt*16 + l15;
    bf16x8 Bf = *(const bf16x8*)(g_w1F + ((0*8 + Nt)*64 + lane)*8);
    f32x4 d = __builtin_amdgcn_mfma_f32_16x16x32_bf16(Af, Bf, zero4, 0, 0, 0);
    const float c1v = g_c1[0*Hd + n];
    bf16x4 hw;
    #pragma unroll
    for (int r = 0; r < 4; ++r) hw[r] = (__bf16)(d[r] + c1v * gq[r]);
    *(bf16x4*)(hT + n*NSTR + nodeBase + quad*4) = hw;
  }
  __syncthreads();

  // ---- P0: read multiplicity + scatter head-0 coeffs into Pbf[0] ----
  float fm = 0.f;
  if (tid < NE && rep) {
    fm = (float)cells[ecell];
    float e = sS1s[0][es] + sS1d[0][et];
    e = (e > 0.f) ? e : 0.2f * e;
    float pe = fm * __expf(e);
    Pbf[0][et*PROW + es] = (__bf16)pe;
    atomicAdd(SUMP(0, et), pe);
  }
  __syncthreads();                                    // cells dead; eluS free from here

  f32x4 acc[8];                                       // GEMM2 accumulators
  #pragma unroll
  for (int i = 0; i < 8; ++i) acc[i] = zero4;
  f32x4 accS = zero4;                                 // layer-2 score accumulator

  #pragma unroll 1                                    // keep head loop rolled (R9)
  for (int hh = 0; hh < HEADS; ++hh) {
    const int cur = hh & 1;                           // buffer read by this C
    // ---- C(hh): out^T = hT @ P^T; epilogue 1/sum, +b1, ELU -> eluS ----
    {
      bf16x8 Ac[2][2];
      #pragma unroll
      for (int Mi = 0; Mi < 2; ++Mi)
        #pragma unroll
        for (int Ks = 0; Ks < 2; ++Ks)
          Ac[Mi][Ks] = *(const bf16x8*)(hT + (m0 + Mi*16 + l15)*NSTR + Ks*32 + quad*8);
      float4 b1v[2];
      #pragma unroll
      for (int Mi = 0; Mi < 2; ++Mi)
        b1v[Mi] = *(const float4*)&b1[hh*Hd + m0 + Mi*16 + quad*4];
      #pragma unroll
      for (int Nt = 0; Nt < 4; ++Nt) {
        bf16x8 B0f = *(const bf16x8*)(Pbf[cur] + (Nt*16 + l15)*PROW + quad*8);
        bf16x8 B1f = *(const bf16x8*)(Pbf[cur] + (Nt*16 + l15)*PROW + 32 + quad*8);
        const int t = Nt*16 + l15;
        const float si = RCP(*SUMP(cur, t) + 1e-16f);
        #pragma unroll
        for (int Mi = 0; Mi < 2; ++Mi) {
          f32x4 d = __builtin_amdgcn_mfma_f32_16x16x32_bf16(Ac[Mi][0], B0f, zero4, 0, 0, 0);
          d = __builtin_amdgcn_mfma_f32_16x16x32_bf16(Ac[Mi][1], B1f, d, 0, 0, 0);
          bf16x4 w;
          #pragma unroll
          for (int r = 0; r < 4; ++r) {
            float hv = d[r]*si + b1v[Mi][r];
            hv = (hv > 0.f) ? hv : (__expf(hv) - 1.f);
            w[r] = (__bf16)hv;
          }
          *(bf16x4*)(eluS + t*EROW + m0 + Mi*16 + quad*4) = w;
        }
      }
    }
    if (hh >= 1) {                                    // zero buffer for NEXT scatter
      float4* p4 = (float4*)&Pbf[(hh+1)&1][0];        // hh=1->0, hh=2->1, hh=3->0(layer2)
      const float4 z4 = {0.f,0.f,0.f,0.f};
      p4[tid] = z4; p4[tid + 256] = z4;
      if (tid < 32) p4[tid + 512] = z4;
    }
    __syncthreads();

    // ---- D(hh): GEMM2 + score col; stage next head (A + scatter) or E ----
    #pragma unroll
    for (int Ks = 0; Ks < 4; ++Ks) {
      bf16x8 A2 = *(const bf16x8*)(eluS + (nodeBase + l15)*EROW + Ks*32 + quad*8);
      #pragma unroll
      for (int Nt = 0; Nt < 8; ++Nt) {
        bf16x8 B2 = *(const bf16x8*)(g_w2F + (((hh*4 + Ks)*8 + Nt)*64 + lane)*8);
        acc[Nt] = __builtin_amdgcn_mfma_f32_16x16x32_bf16(A2, B2, acc[Nt], 0, 0, 0);
      }
      bf16x8 Bs2 = *(const bf16x8*)(g_wscF + ((hh*4 + Ks)*64 + lane)*8);
      accS = __builtin_amdgcn_mfma_f32_16x16x32_bf16(A2, Bs2, accS, 0, 0, 0);
    }
    if (hh < 3) {                                     // A(hh+1): GEMM1 next head -> hT
      #pragma unroll
      for (int Nt = 0; Nt < 8; ++Nt) {
        const int n = Nt*16 + l15;
        bf16x8 Bf = *(const bf16x8*)(g_w1F + (((hh+1)*8 + Nt)*64 + lane)*8);
        f32x4 d = __builtin_amdgcn_mfma_f32_16x16x32_bf16(Af, Bf, zero4, 0, 0, 0);
        const float c1v = g_c1[(hh+1)*Hd + n];
        bf16x4 hw;
        #pragma unroll
        for (int r = 0; r < 4; ++r) hw[r] = (__bf16)(d[r] + c1v * gq[r]);
        *(bf16x4*)(hT + n*NSTR + nodeBase + quad*4) = hw;
      }
      if (tid < NE && rep) {                          // scatter(hh+1) into zeroed buffer
        float e = sS1s[hh+1][es] + sS1d[hh+1][et];
        e = (e > 0.f) ? e : 0.2f * e;
        float pe = fm * __expf(e);
        Pbf[(hh+1)&1][et*PROW + es] = (__bf16)pe;
        atomicAdd(SUMP((hh+1)&1, et), pe);
      }
    } else {                                          // E: publish h2 -> hT, scores -> sSrc/sDst
      #pragma unroll
      for (int Nt = 0; Nt < 8; ++Nt) {
        const int n = Nt*16 + l15;
        bf16x4 hw;
        #pragma unroll
        for (int r = 0; r < 4; ++r) hw[r] = (__bf16)acc[Nt][r];
        *(bf16x4*)(hT + n*NSTR + nodeBase + quad*4) = hw;
      }
      if (l15 == 0) {
        #pragma unroll
        for (int r = 0; r < 4; ++r) sSrc[nodeBase + quad*4 + r] = accS[r];
      } else if (l15 == 1) {
        #pragma unroll
        for (int r = 0; r < 4; ++r) sDst[nodeBase + quad*4 + r] = accS[r];
      }
    }
    __syncthreads();
  }

  // ---- F: layer-2 edge scatter into Pbf[0] (zeroed in C(3)) ----
  if (tid < NE && rep) {
    float e = sSrc[es] + sDst[et];
    e = (e > 0.f) ? e : 0.2f * e;
    float pe = fm * __expf(e);
    Pbf[0][et*PROW + es] = (__bf16)pe;
    atomicAdd(SUMP(0, et), pe);
  }
  __syncthreads();

  // ================= wave-0-only barrier-free tail =================
  if (wv != 0) return;                                // waves 1-3 retire early

  // ---- W: w[s] = (1/64) * sum_t sInv_t * P2[t][s]; lane = s ----
  {
    float sinv = RCP(*SUMP(0, lane) + 1e-16f);        // lane t holds 1/sum_t
    float a = 0.f;
    #pragma unroll 8
    for (int t = 0; t < Fn; ++t)
      a += __shfl(sinv, t) * (float)Pbf[0][t*PROW + lane];
    wS[lane] = (__bf16)(a * (1.f/64.f));
  }

  // ---- G: gpool[f] = h2^T[f] · w + b2[f]; all 8 bands on wave 0 ----
  #pragma unroll
  for (int Mi = 0; Mi < 8; ++Mi) {
    f32x4 d = zero4;
    #pragma unroll
    for (int Ks = 0; Ks < 2; ++Ks) {
      bf16x8 A = *(const bf16x8*)(hT + (Mi*16 + l15)*NSTR + Ks*32 + quad*8);
      bf16x8 Bw = *(const bf16x8*)(wS + Ks*32 + quad*8);   // broadcast
      d = __builtin_amdgcn_mfma_f32_16x16x32_bf16(A, Bw, d, 0, 0, 0);
    }
    if (l15 == 0) {
      #pragma unroll
      for (int r = 0; r < 4; ++r) {
        const int f = Mi*16 + quad*4 + r;
        gpool[f] = d[r] + b2[f];
      }
    }
  }

  // ---- classifier layer 1: lane = col ----
  {
    float a = 0.f;
    #pragma unroll 8
    for (int k = 0; k < Hd; ++k)
      a += gpool[k] * Wc1[k*Fn + lane];
    a += bc1[lane];
    hcS[lane] = (a > 0.f) ? a : 0.01f * a;
  }

  // ---- classifier layer 2: 4 lanes/col ----
  {
    const int c = lane & 15, part = lane >> 4;
    float a = 0.f;
    #pragma unroll
    for (int i = 0; i < 16; ++i) {
      const int k = part*16 + i;
      a += hcS[k] * Wc2[k*NC + c];
    }
    a += __shfl_xor(a, 16);
    a += __shfl_xor(a, 32);
    if (part == 0) out[b*NC + c] = a + bc2[c];
  }
}
#undef SUMP
#undef RCP

extern "C" void kernel_launch(void* const* d_in, const int* in_sizes, int n_in,
                              void* d_out, int out_size, void* d_ws, size_t ws_size,
                              hipStream_t stream) {
  const float* emb = (const float*)d_in[0];
  const int*   ei  = (const int*)  d_in[1];
  // d_in[2] = batch_idx (layout known)
  const float* Wa  = (const float*)d_in[3];
  const float* ba  = (const float*)d_in[4];
  const float* gl  = (const float*)d_in[5];
  const float* W1  = (const float*)d_in[6];
  const float* as1 = (const float*)d_in[7];
  const float* ad1 = (const float*)d_in[8];
  const float* b1  = (const float*)d_in[9];
  const float* W2  = (const float*)d_in[10];
  const float* as2 = (const float*)d_in[11];
  const float* ad2 = (const float*)d_in[12];
  const float* b2  = (const float*)d_in[13];
  const float* Wc1 = (const float*)d_in[14];
  const float* bc1 = (const float*)d_in[15];
  const float* Wc2 = (const float*)d_in[16];
  const float* bc2 = (const float*)d_in[17];
  float* out = (float*)d_out;

  const int prep1N = DIN*W1C + W1C;                     // 16896
  hipLaunchKernelGGL(prep1, dim3((prep1N + BLK - 1)/BLK), dim3(BLK), 0, stream,
                     Wa, ba, W1);
  hipLaunchKernelGGL(prep2, dim3((P2_TOT + BLK - 1)/BLK), dim3(BLK), 0, stream,
                     W2, as1, ad1, as2, ad2);
  hipLaunchKernelGGL(gat_main, dim3(Bg), dim3(BLK), 0, stream,
                     emb, ei, gl, b1, b2, Wc1, bc1, Wc2, bc2, out);
}